// Round 2
// baseline (2270.959 us; speedup 1.0000x reference)
//
#include <hip/hip_runtime.h>
#include <hip/hip_bf16.h>
#include <cstdint>
#include <cstddef>

// ---------------------------------------------------------------------------
// MeshDecoder pipeline. All tensors fp32 (per reference dtypes).
// Activations kept in transposed layout (B, E, C) so the per-element neighbor
// gathers read contiguous C-length rows (coalesced float4).
// Weights pre-transposed to W_T[k][o], k = c*5+s, so the conv inner loop reads
// W coalesced (float4 across o).
// ---------------------------------------------------------------------------

// (B,C,E) fp32 -> (B,E,C) fp32 tiled transpose
__global__ __launch_bounds__(256) void k_transpose_in(
    const float* __restrict__ in, float* __restrict__ out, int C, int E)
{
    __shared__ float tile[64][65];
    const int e0 = blockIdx.x * 64;
    const int c0 = blockIdx.y * 64;
    const int b  = blockIdx.z;
    const float* inb = in + (size_t)b * C * E;
    const int l = threadIdx.x % 64;   // fast index
    const int g = threadIdx.x / 64;   // 0..3
#pragma unroll
    for (int i = 0; i < 16; ++i) {
        const int c = i * 4 + g;
        tile[c][l] = inb[(size_t)(c0 + c) * E + e0 + l];
    }
    __syncthreads();
    float* outb = out + (size_t)b * E * C;
#pragma unroll
    for (int i = 0; i < 16; ++i) {
        const int e = i * 4 + g;
        outb[(size_t)(e0 + e) * C + c0 + l] = tile[l][e];
    }
}

// W (O,C,5) fp32 -> W_T[(c*5+s)*O + o] fp32
__global__ __launch_bounds__(256) void k_prep_w(
    const float* __restrict__ W, float* __restrict__ Wt, int C, int O)
{
    const int idx = blockIdx.x * 256 + threadIdx.x;
    const int total = C * 5 * O;
    if (idx >= total) return;
    const int k = idx / O;
    const int o = idx % O;
    const int c = k / 5;
    const int s = k - 5 * c;
    Wt[idx] = W[((size_t)o * C + c) * 5 + s];
}

// mesh_conv: x (B,E,C) fp32, gm (E,4), Wt (5C,O) fp32, bias (O) fp32 -> out (B,E,O)
template<int C, int O, int R_O, int R_E>
__global__ __launch_bounds__(256) void k_conv(
    const float* __restrict__ x, const int* __restrict__ gm,
    const float* __restrict__ Wt, const float* __restrict__ bias,
    float* __restrict__ out, int E)
{
    constexpr int OG = O / R_O;        // o-groups per block
    constexpr int EG = 256 / OG;       // e-groups per block
    constexpr int TILE_E = EG * R_E;
    static_assert(O % R_O == 0 && 256 % OG == 0, "bad cfg");
    const int tid = threadIdx.x;
    const int og  = tid % OG;
    const int eg  = tid / OG;
    const int b   = blockIdx.y;
    const int e0  = blockIdx.x * TILE_E + eg * R_E;
    const int o0  = og * R_O;
    const float* xb = x + (size_t)b * E * C;

    const float* rp[R_E][5];
#pragma unroll
    for (int j = 0; j < R_E; ++j) {
        const int e = e0 + j;
        const int4 gi = *reinterpret_cast<const int4*>(gm + 4 * e);
        rp[j][0] = xb + (size_t)e * C;
        rp[j][1] = xb + (size_t)gi.x * C;
        rp[j][2] = xb + (size_t)gi.y * C;
        rp[j][3] = xb + (size_t)gi.z * C;
        rp[j][4] = xb + (size_t)gi.w * C;
    }

    float acc[R_E][R_O];
#pragma unroll
    for (int j = 0; j < R_E; ++j)
#pragma unroll
        for (int r = 0; r < R_O; ++r) acc[j][r] = 0.f;

    for (int c = 0; c < C; c += 4) {
        float4 xv[R_E][5];
#pragma unroll
        for (int j = 0; j < R_E; ++j)
#pragma unroll
            for (int k = 0; k < 5; ++k)
                xv[j][k] = *reinterpret_cast<const float4*>(rp[j][k] + c);

#pragma unroll
        for (int cc = 0; cc < 4; ++cc) {
            float gv[R_E][5];
#pragma unroll
            for (int j = 0; j < R_E; ++j) {
                const float x0 = ((const float*)&xv[j][0])[cc];
                const float f1 = ((const float*)&xv[j][1])[cc];
                const float f2 = ((const float*)&xv[j][2])[cc];
                const float f3 = ((const float*)&xv[j][3])[cc];
                const float f4 = ((const float*)&xv[j][4])[cc];
                gv[j][0] = x0;
                gv[j][1] = f1 + f3;
                gv[j][2] = f2 + f4;
                gv[j][3] = fabsf(f1 - f3);
                gv[j][4] = fabsf(f2 - f4);
            }
            const float* wbase = Wt + ((size_t)(c + cc) * 5) * O + o0;
#pragma unroll
            for (int s = 0; s < 5; ++s) {
                const float4 wv = *reinterpret_cast<const float4*>(wbase + (size_t)s * O);
#pragma unroll
                for (int j = 0; j < R_E; ++j) {
                    acc[j][0] += gv[j][s] * wv.x;
                    acc[j][1] += gv[j][s] * wv.y;
                    acc[j][2] += gv[j][s] * wv.z;
                    acc[j][3] += gv[j][s] * wv.w;
                }
            }
        }
    }

    float bo[R_O];
#pragma unroll
    for (int r = 0; r < R_O; ++r) bo[r] = bias[o0 + r];

#pragma unroll
    for (int j = 0; j < R_E; ++j) {
        float4 v;
        v.x = acc[j][0] + bo[0];
        v.y = acc[j][1] + bo[1];
        v.z = acc[j][2] + bo[2];
        v.w = acc[j][3] + bo[3];
        *reinterpret_cast<float4*>(out + ((size_t)b * E + (e0 + j)) * O + o0) = v;
    }
}

// x1[b,e',o] = y[b, up[e'], o] + skip[b, o, e']
template<int O>
__global__ __launch_bounds__(256) void k_unpool_skip(
    const float* __restrict__ y, const int* __restrict__ up,
    const float* __restrict__ skip, float* __restrict__ out,
    int Ein, int Eout)
{
    const int b = blockIdx.y;
    const int idx = blockIdx.x * 256 + threadIdx.x;  // over Eout*O
    const int e = idx / O;
    const int o = idx % O;
    const int u = up[e];
    const float v = y[((size_t)b * Ein + u) * O + o]
                  + skip[((size_t)b * O + o) * Eout + e];
    out[((size_t)b * Eout + e) * O + o] = v;
}

// per-(b,c) sum / sumsq partials over 256-e chunks, atomically accumulated
template<int C>
__global__ __launch_bounds__(256) void k_stats(
    const float* __restrict__ x, float* __restrict__ stats, int E)
{
    constexpr int J = 256 / C;
    __shared__ float ssum[256];
    __shared__ float ssq[256];
    const int tid = threadIdx.x;
    const int c = tid % C;
    const int j = tid / C;
    const int b = blockIdx.y;
    const float* xb = x + ((size_t)b * E + (size_t)blockIdx.x * 256) * C;
    float s = 0.f, q = 0.f;
    for (int e = j; e < 256; e += J) {
        const float v = xb[(size_t)e * C + c];
        s += v; q += v * v;
    }
    ssum[tid] = s; ssq[tid] = q;
    __syncthreads();
    for (int st = 128; st >= C; st >>= 1) {
        if (tid < st) { ssum[tid] += ssum[tid + st]; ssq[tid] += ssq[tid + st]; }
        __syncthreads();
    }
    if (tid < C) {
        atomicAdd(&stats[((size_t)b * C + c) * 2], ssum[tid]);
        atomicAdd(&stats[((size_t)b * C + c) * 2 + 1], ssq[tid]);
    }
}

// stats -> scale/shift
__global__ __launch_bounds__(256) void k_scale(
    const float* __restrict__ stats, float* __restrict__ ss, int BC, float invE)
{
    const int t = threadIdx.x;
    if (t < BC) {
        const float sum = stats[t * 2];
        const float sq  = stats[t * 2 + 1];
        const float m   = sum * invE;
        const float var = fmaxf(sq * invE - m * m, 0.f);
        const float sc  = rsqrtf(var + 1e-5f);
        ss[t * 2] = sc;
        ss[t * 2 + 1] = -m * sc;
    }
}

// in-place relu((x-m)*rsqrt(var+eps))
template<int C>
__global__ __launch_bounds__(256) void k_norm_relu(
    float* __restrict__ x, const float* __restrict__ ss, int E)
{
    const int b = blockIdx.y;
    const size_t idx = (size_t)blockIdx.x * 256 + threadIdx.x;
    const int c = (int)(idx % C);
    const float sc = ss[((size_t)b * C + c) * 2];
    const float sh = ss[((size_t)b * C + c) * 2 + 1];
    float* p = x + (size_t)b * E * C + idx;
    *p = fmaxf(*p * sc + sh, 0.f);
}

// final: (B,E,8) fp32 -> norm+relu -> (B,8,E) fp32
__global__ __launch_bounds__(256) void k_final_out(
    const float* __restrict__ z, const float* __restrict__ ss,
    float* __restrict__ out, int E)
{
    const int b = blockIdx.y;
    const int idx = blockIdx.x * 256 + threadIdx.x;  // over 8*E
    const int o = idx / E;
    const int e = idx % E;
    const float sc = ss[((size_t)b * 8 + o) * 2];
    const float sh = ss[((size_t)b * 8 + o) * 2 + 1];
    const float v = z[((size_t)b * E + e) * 8 + o] * sc + sh;
    out[(size_t)b * 8 * E + idx] = fmaxf(v, 0.f);
}

extern "C" void kernel_launch(void* const* d_in, const int* in_sizes, int n_in,
                              void* d_out, int out_size, void* d_ws, size_t ws_size,
                              hipStream_t stream)
{
    (void)in_sizes; (void)n_in; (void)out_size; (void)ws_size;

    const float* fe    = (const float*)d_in[0];
    const float* skip0 = (const float*)d_in[1];
    const float* skip1 = (const float*)d_in[2];
    const float* skip2 = (const float*)d_in[3];
    const int* gemm0 = (const int*)d_in[4];
    const int* gemm1 = (const int*)d_in[5];
    const int* gemm2 = (const int*)d_in[6];
    const int* gemm3 = (const int*)d_in[7];
    const int* up0 = (const int*)d_in[8];
    const int* up1 = (const int*)d_in[9];
    const int* up2 = (const int*)d_in[10];
    const float* bup0 = (const float*)d_in[12];
    const float* bc0  = (const float*)d_in[14];
    const float* bup1 = (const float*)d_in[16];
    const float* bc1  = (const float*)d_in[18];
    const float* bup2 = (const float*)d_in[20];
    const float* bc2  = (const float*)d_in[22];
    const float* bupf = (const float*)d_in[24];
    const float* bcf  = (const float*)d_in[26];

    float* ws = (float*)d_ws;
    const size_t NP = 8388608;  // 2*32768*128 = max activation elems
    float* P0 = ws;
    float* P1 = ws + NP;
    float* P2 = ws + 2 * NP;
    float* wt_up0 = ws + 3 * NP;          // 256*5*128 = 163840
    float* wt_c0  = wt_up0 + 163840;      // 128*5*128 =  81920
    float* wt_up1 = wt_c0  + 81920;       // 128*5*64  =  40960
    float* wt_c1  = wt_up1 + 40960;       //  64*5*64  =  20480
    float* wt_up2 = wt_c1  + 20480;       //  64*5*32  =  10240
    float* wt_c2  = wt_up2 + 10240;       //  32*5*32  =   5120
    float* wt_upf = wt_c2  + 5120;        //  32*5*8   =   1280
    float* wt_cf  = wt_upf + 1280;        //   8*5*8   =    320
    float* stats0 = wt_cf  + 320;         // 2*128*2 = 512
    float* stats1 = stats0 + 512;         // 2*64*2  = 256
    float* stats2 = stats1 + 256;         // 2*32*2  = 128
    float* stats3 = stats2 + 128;         // 2*8*2   = 32
    float* ss0    = stats3 + 32;
    float* ss1    = ss0 + 512;
    float* ss2    = ss1 + 256;
    float* ss3    = ss2 + 128;

    // zero all stats accumulators (928 floats)
    hipMemsetAsync(stats0, 0, 928 * sizeof(float), stream);

    const dim3 blk(256);

    // input transpose: fe (2,256,16384) -> P0 (2,16384,256)
    k_transpose_in<<<dim3(16384 / 64, 256 / 64, 2), blk, 0, stream>>>(fe, P0, 256, 16384);

    // weight transposes
    k_prep_w<<<dim3(163840 / 256), blk, 0, stream>>>((const float*)d_in[11], wt_up0, 256, 128);
    k_prep_w<<<dim3(81920 / 256),  blk, 0, stream>>>((const float*)d_in[13], wt_c0, 128, 128);
    k_prep_w<<<dim3(40960 / 256),  blk, 0, stream>>>((const float*)d_in[15], wt_up1, 128, 64);
    k_prep_w<<<dim3(20480 / 256),  blk, 0, stream>>>((const float*)d_in[17], wt_c1, 64, 64);
    k_prep_w<<<dim3(10240 / 256),  blk, 0, stream>>>((const float*)d_in[19], wt_up2, 64, 32);
    k_prep_w<<<dim3(5120 / 256),   blk, 0, stream>>>((const float*)d_in[21], wt_c2, 32, 32);
    k_prep_w<<<dim3((1280 + 255) / 256), blk, 0, stream>>>((const float*)d_in[23], wt_upf, 32, 8);
    k_prep_w<<<dim3((320 + 255) / 256),  blk, 0, stream>>>((const float*)d_in[25], wt_cf, 8, 8);

    // ---- stage 0 ----
    k_conv<256, 128, 4, 2><<<dim3(16384 / 16, 2), blk, 0, stream>>>(P0, gemm0, wt_up0, bup0, P1, 16384);
    k_unpool_skip<128><<<dim3(32768 * 128 / 256, 2), blk, 0, stream>>>(P1, up0, skip0, P2, 16384, 32768);
    k_conv<128, 128, 4, 2><<<dim3(32768 / 16, 2), blk, 0, stream>>>(P2, gemm1, wt_c0, bc0, P0, 32768);
    k_stats<128><<<dim3(32768 / 256, 2), blk, 0, stream>>>(P0, stats0, 32768);
    k_scale<<<dim3(1), blk, 0, stream>>>(stats0, ss0, 256, 1.f / 32768.f);
    k_norm_relu<128><<<dim3(32768 * 128 / 256, 2), blk, 0, stream>>>(P0, ss0, 32768);

    // ---- stage 1 ----
    k_conv<128, 64, 4, 2><<<dim3(32768 / 32, 2), blk, 0, stream>>>(P0, gemm1, wt_up1, bup1, P1, 32768);
    k_unpool_skip<64><<<dim3(65536 * 64 / 256, 2), blk, 0, stream>>>(P1, up1, skip1, P2, 32768, 65536);
    k_conv<64, 64, 4, 2><<<dim3(65536 / 32, 2), blk, 0, stream>>>(P2, gemm2, wt_c1, bc1, P0, 65536);
    k_stats<64><<<dim3(65536 / 256, 2), blk, 0, stream>>>(P0, stats1, 65536);
    k_scale<<<dim3(1), blk, 0, stream>>>(stats1, ss1, 128, 1.f / 65536.f);
    k_norm_relu<64><<<dim3(65536 * 64 / 256, 2), blk, 0, stream>>>(P0, ss1, 65536);

    // ---- stage 2 ----
    k_conv<64, 32, 4, 2><<<dim3(65536 / 64, 2), blk, 0, stream>>>(P0, gemm2, wt_up2, bup2, P1, 65536);
    k_unpool_skip<32><<<dim3(131072 * 32 / 256, 2), blk, 0, stream>>>(P1, up2, skip2, P2, 65536, 131072);
    k_conv<32, 32, 4, 2><<<dim3(131072 / 64, 2), blk, 0, stream>>>(P2, gemm3, wt_c2, bc2, P0, 131072);
    k_stats<32><<<dim3(131072 / 256, 2), blk, 0, stream>>>(P0, stats2, 131072);
    k_scale<<<dim3(1), blk, 0, stream>>>(stats2, ss2, 64, 1.f / 131072.f);
    k_norm_relu<32><<<dim3(131072 * 32 / 256, 2), blk, 0, stream>>>(P0, ss2, 131072);

    // ---- final ----
    k_conv<32, 8, 4, 2><<<dim3(131072 / 256, 2), blk, 0, stream>>>(P0, gemm3, wt_upf, bupf, P1, 131072);
    k_conv<8, 8, 4, 2><<<dim3(131072 / 256, 2), blk, 0, stream>>>(P1, gemm3, wt_cf, bcf, P2, 131072);
    k_stats<8><<<dim3(131072 / 256, 2), blk, 0, stream>>>(P2, stats3, 131072);
    k_scale<<<dim3(1), blk, 0, stream>>>(stats3, ss3, 16, 1.f / 131072.f);
    k_final_out<<<dim3(8 * 131072 / 256, 2), blk, 0, stream>>>(P2, ss3, (float*)d_out, 131072);
}

// Round 3
// 801.353 us; speedup vs baseline: 2.8339x; 2.8339x over previous
//
#include <hip/hip_runtime.h>
#include <hip/hip_bf16.h>
#include <cstdint>
#include <cstddef>

// ---------------------------------------------------------------------------
// MeshDecoder pipeline, round 3: bf16 activations + MFMA convs.
// Activations: bf16, layout (B, E, C) with C contiguous (gather-friendly rows).
// Big convs (C>=32, O>=32... actually O>=16): mfma_f32_16x16x32_bf16.
//   K ordered k = s*C + c  (s = which of the 5 G-segments).
//   A-fragment layout: A[m=lane&15][k=(lane>>4)*8+j]  (m120-verified)
//   B-fragment layout: B[k=(lane>>4)*8+j][n=lane&15]  -> pre-packed Bp[kk][o][j]
//   C/D layout: col=lane&15, row=(lane>>4)*4+reg      (m89/m91-verified)
// Tiny convs (O=8): fp32 VALU path on bf16 I/O.
// ---------------------------------------------------------------------------

typedef short s16x8 __attribute__((ext_vector_type(8)));
typedef float f32x4 __attribute__((ext_vector_type(4)));

__device__ __forceinline__ float bfbits2f(unsigned short u) {
    unsigned int x = ((unsigned int)u) << 16;
    float f; __builtin_memcpy(&f, &x, sizeof(f)); return f;
}
__device__ __forceinline__ unsigned short f2bfbits(float f) {
    __hip_bfloat16 h = __float2bfloat16(f);
    unsigned short u; __builtin_memcpy(&u, &h, sizeof(u)); return u;
}

// (B,C,E) fp32 -> (B,E,C) bf16 tiled transpose
__global__ __launch_bounds__(256) void k_transpose_in(
    const float* __restrict__ in, unsigned short* __restrict__ out, int C, int E)
{
    __shared__ float tile[64][65];
    const int e0 = blockIdx.x * 64;
    const int c0 = blockIdx.y * 64;
    const int b  = blockIdx.z;
    const float* inb = in + (size_t)b * C * E;
    const int l = threadIdx.x % 64;
    const int g = threadIdx.x / 64;
#pragma unroll
    for (int i = 0; i < 16; ++i) {
        const int c = i * 4 + g;
        tile[c][l] = inb[(size_t)(c0 + c) * E + e0 + l];
    }
    __syncthreads();
    unsigned short* outb = out + (size_t)b * E * C;
#pragma unroll
    for (int i = 0; i < 16; ++i) {
        const int e = i * 4 + g;
        outb[(size_t)(e0 + e) * C + c0 + l] = f2bfbits(tile[l][e]);
    }
}

// W (O,C,5) fp32 -> B-fragment-packed bf16: Bp[((kk*O)+o)*8 + j], k=kk*8+j=s*C+c
__global__ __launch_bounds__(256) void k_prep_b(
    const float* __restrict__ W, unsigned short* __restrict__ Bp, int C, int O)
{
    const int p = blockIdx.x * 256 + threadIdx.x;
    const int total = 5 * C * O;
    if (p >= total) return;
    const int j = p & 7;
    const int t = p >> 3;
    const int o = t % O;
    const int kk = t / O;
    const int k = kk * 8 + j;
    const int s = k / C;
    const int c = k - s * C;
    Bp[p] = f2bfbits(W[((size_t)o * C + c) * 5 + s]);
}

// W (O,C,5) fp32 -> W_T[(c*5+s)*O + o] fp32 (VALU-path weights)
__global__ __launch_bounds__(256) void k_prep_w(
    const float* __restrict__ W, float* __restrict__ Wt, int C, int O)
{
    const int idx = blockIdx.x * 256 + threadIdx.x;
    const int total = C * 5 * O;
    if (idx >= total) return;
    const int k = idx / O;
    const int o = idx % O;
    const int c = k / 5;
    const int s = k - 5 * c;
    Wt[idx] = W[((size_t)o * C + c) * 5 + s];
}

// MFMA mesh_conv: x (B,E,C) bf16, gm (E,4), Bp packed bf16, bias fp32 -> out (B,E,O) bf16
template<int C, int O>
__global__ __launch_bounds__(256) void k_conv_mfma(
    const unsigned short* __restrict__ x, const int* __restrict__ gm,
    const unsigned short* __restrict__ Bp, const float* __restrict__ bias,
    unsigned short* __restrict__ out, int E)
{
    constexpr int NT  = O / 16;     // N-tiles
    constexpr int ITS = C / 32;     // K-steps per G-segment
    static_assert(C % 32 == 0 && O % 16 == 0, "bad cfg");
    const int tid  = threadIdx.x;
    const int wave = tid >> 6;
    const int lane = tid & 63;
    const int m    = lane & 15;     // A-row within tile / D-col (o)
    const int kq   = lane >> 4;     // k-quad
    const int b    = blockIdx.y;
    const int e    = blockIdx.x * 64 + wave * 16 + m;
    const unsigned short* xb = x + (size_t)b * E * C;

    const int4 gi = *reinterpret_cast<const int4*>(gm + 4 * (size_t)e);
    const unsigned short* p0  = xb + (size_t)e * C;
    const unsigned short* pf1 = xb + (size_t)gi.x * C;
    const unsigned short* pf2 = xb + (size_t)gi.y * C;
    const unsigned short* pf3 = xb + (size_t)gi.z * C;
    const unsigned short* pf4 = xb + (size_t)gi.w * C;

    const s16x8* Bp8 = reinterpret_cast<const s16x8*>(Bp);

    f32x4 acc[NT];
#pragma unroll
    for (int nt = 0; nt < NT; ++nt) acc[nt] = (f32x4){0.f, 0.f, 0.f, 0.f};

#pragma unroll
    for (int s = 0; s < 5; ++s) {
        // G_0 = x[e]; G_1 = f1+f3; G_2 = f2+f4; G_3 = |f1-f3|; G_4 = |f2-f4|
        const unsigned short* pa = (s == 0) ? p0 : ((s == 1 || s == 3) ? pf1 : pf2);
        const unsigned short* pb = (s == 0) ? p0 : ((s == 1 || s == 3) ? pf3 : pf4);
        for (int it = 0; it < ITS; ++it) {
            const int c0 = it * 32 + kq * 8;
            s16x8 afrag;
            if (s == 0) {
                afrag = *reinterpret_cast<const s16x8*>(pa + c0);
            } else {
                const s16x8 av = *reinterpret_cast<const s16x8*>(pa + c0);
                const s16x8 bv = *reinterpret_cast<const s16x8*>(pb + c0);
#pragma unroll
                for (int j = 0; j < 8; ++j) {
                    const float fa = bfbits2f((unsigned short)av[j]);
                    const float fb = bfbits2f((unsigned short)bv[j]);
                    const float t = (s < 3) ? (fa + fb) : fabsf(fa - fb);
                    afrag[j] = (short)f2bfbits(t);
                }
            }
            const int kk = s * (C / 8) + it * 4 + kq;
#pragma unroll
            for (int nt = 0; nt < NT; ++nt) {
                const s16x8 bfrag = Bp8[(size_t)kk * O + nt * 16 + m];
                acc[nt] = __builtin_amdgcn_mfma_f32_16x16x32_bf16(afrag, bfrag, acc[nt], 0, 0, 0);
            }
        }
    }

    const int ebase = blockIdx.x * 64 + wave * 16 + kq * 4;
#pragma unroll
    for (int nt = 0; nt < NT; ++nt) {
        const int o = nt * 16 + m;
        const float bo = bias[o];
#pragma unroll
        for (int r = 0; r < 4; ++r) {
            out[((size_t)b * E + (ebase + r)) * O + o] = f2bfbits(acc[nt][r] + bo);
        }
    }
}

// VALU mesh_conv for tiny O: x bf16, Wt fp32 (k=c*5+s layout), out bf16
template<int C, int O, int R_O, int R_E>
__global__ __launch_bounds__(256) void k_conv_small(
    const unsigned short* __restrict__ x, const int* __restrict__ gm,
    const float* __restrict__ Wt, const float* __restrict__ bias,
    unsigned short* __restrict__ out, int E)
{
    constexpr int OG = O / R_O;
    constexpr int EG = 256 / OG;
    constexpr int TILE_E = EG * R_E;
    static_assert(O % R_O == 0 && 256 % OG == 0, "bad cfg");
    const int tid = threadIdx.x;
    const int og  = tid % OG;
    const int eg  = tid / OG;
    const int b   = blockIdx.y;
    const int e0  = blockIdx.x * TILE_E + eg * R_E;
    const int o0  = og * R_O;
    const unsigned short* xb = x + (size_t)b * E * C;

    const unsigned short* rp[R_E][5];
#pragma unroll
    for (int j = 0; j < R_E; ++j) {
        const int e = e0 + j;
        const int4 gi = *reinterpret_cast<const int4*>(gm + 4 * (size_t)e);
        rp[j][0] = xb + (size_t)e * C;
        rp[j][1] = xb + (size_t)gi.x * C;
        rp[j][2] = xb + (size_t)gi.y * C;
        rp[j][3] = xb + (size_t)gi.z * C;
        rp[j][4] = xb + (size_t)gi.w * C;
    }

    float acc[R_E][R_O];
#pragma unroll
    for (int j = 0; j < R_E; ++j)
#pragma unroll
        for (int r = 0; r < R_O; ++r) acc[j][r] = 0.f;

    for (int c = 0; c < C; c += 4) {
        float xv[R_E][5][4];
#pragma unroll
        for (int j = 0; j < R_E; ++j)
#pragma unroll
            for (int k = 0; k < 5; ++k) {
                const ushort4 raw = *reinterpret_cast<const ushort4*>(rp[j][k] + c);
                xv[j][k][0] = bfbits2f(raw.x);
                xv[j][k][1] = bfbits2f(raw.y);
                xv[j][k][2] = bfbits2f(raw.z);
                xv[j][k][3] = bfbits2f(raw.w);
            }
#pragma unroll
        for (int cc = 0; cc < 4; ++cc) {
            float gv[R_E][5];
#pragma unroll
            for (int j = 0; j < R_E; ++j) {
                const float x0 = xv[j][0][cc];
                const float f1 = xv[j][1][cc];
                const float f2 = xv[j][2][cc];
                const float f3 = xv[j][3][cc];
                const float f4 = xv[j][4][cc];
                gv[j][0] = x0;
                gv[j][1] = f1 + f3;
                gv[j][2] = f2 + f4;
                gv[j][3] = fabsf(f1 - f3);
                gv[j][4] = fabsf(f2 - f4);
            }
            const float* wbase = Wt + ((size_t)(c + cc) * 5) * O + o0;
#pragma unroll
            for (int s = 0; s < 5; ++s) {
                const float4 wv = *reinterpret_cast<const float4*>(wbase + (size_t)s * O);
#pragma unroll
                for (int j = 0; j < R_E; ++j) {
                    acc[j][0] += gv[j][s] * wv.x;
                    acc[j][1] += gv[j][s] * wv.y;
                    acc[j][2] += gv[j][s] * wv.z;
                    acc[j][3] += gv[j][s] * wv.w;
                }
            }
        }
    }

#pragma unroll
    for (int j = 0; j < R_E; ++j) {
        ushort4 v;
        v.x = f2bfbits(acc[j][0] + bias[o0 + 0]);
        v.y = f2bfbits(acc[j][1] + bias[o0 + 1]);
        v.z = f2bfbits(acc[j][2] + bias[o0 + 2]);
        v.w = f2bfbits(acc[j][3] + bias[o0 + 3]);
        *reinterpret_cast<ushort4*>(out + ((size_t)b * E + (e0 + j)) * O + o0) = v;
    }
}

// x1[b,e',o] = y[b, up[e'], o] + skip[b, o, e']
template<int O>
__global__ __launch_bounds__(256) void k_unpool_skip(
    const unsigned short* __restrict__ y, const int* __restrict__ up,
    const float* __restrict__ skip, unsigned short* __restrict__ out,
    int Ein, int Eout)
{
    const int b = blockIdx.y;
    const int idx = blockIdx.x * 256 + threadIdx.x;  // over Eout*O
    const int e = idx / O;
    const int o = idx % O;
    const int u = up[e];
    const float v = bfbits2f(y[((size_t)b * Ein + u) * O + o])
                  + skip[((size_t)b * O + o) * Eout + e];
    out[((size_t)b * Eout + e) * O + o] = f2bfbits(v);
}

// per-(b,c) sum / sumsq partials over 256-e chunks, atomically accumulated
template<int C>
__global__ __launch_bounds__(256) void k_stats(
    const unsigned short* __restrict__ x, float* __restrict__ stats, int E)
{
    constexpr int J = 256 / C;
    __shared__ float ssum[256];
    __shared__ float ssq[256];
    const int tid = threadIdx.x;
    const int c = tid % C;
    const int j = tid / C;
    const int b = blockIdx.y;
    const unsigned short* xb = x + ((size_t)b * E + (size_t)blockIdx.x * 256) * C;
    float s = 0.f, q = 0.f;
    for (int e = j; e < 256; e += J) {
        const float v = bfbits2f(xb[(size_t)e * C + c]);
        s += v; q += v * v;
    }
    ssum[tid] = s; ssq[tid] = q;
    __syncthreads();
    for (int st = 128; st >= C; st >>= 1) {
        if (tid < st) { ssum[tid] += ssum[tid + st]; ssq[tid] += ssq[tid + st]; }
        __syncthreads();
    }
    if (tid < C) {
        atomicAdd(&stats[((size_t)b * C + c) * 2], ssum[tid]);
        atomicAdd(&stats[((size_t)b * C + c) * 2 + 1], ssq[tid]);
    }
}

// stats -> scale/shift
__global__ __launch_bounds__(256) void k_scale(
    const float* __restrict__ stats, float* __restrict__ ss, int BC, float invE)
{
    const int t = threadIdx.x;
    if (t < BC) {
        const float sum = stats[t * 2];
        const float sq  = stats[t * 2 + 1];
        const float m   = sum * invE;
        const float var = fmaxf(sq * invE - m * m, 0.f);
        const float sc  = rsqrtf(var + 1e-5f);
        ss[t * 2] = sc;
        ss[t * 2 + 1] = -m * sc;
    }
}

// in-place relu((x-m)*rsqrt(var+eps)) on bf16
template<int C>
__global__ __launch_bounds__(256) void k_norm_relu(
    unsigned short* __restrict__ x, const float* __restrict__ ss, int E)
{
    const int b = blockIdx.y;
    const size_t idx = (size_t)blockIdx.x * 256 + threadIdx.x;
    const int c = (int)(idx % C);
    const float sc = ss[((size_t)b * C + c) * 2];
    const float sh = ss[((size_t)b * C + c) * 2 + 1];
    unsigned short* p = x + (size_t)b * E * C + idx;
    *p = f2bfbits(fmaxf(bfbits2f(*p) * sc + sh, 0.f));
}

// final: (B,E,8) bf16 -> norm+relu -> (B,8,E) fp32
__global__ __launch_bounds__(256) void k_final_out(
    const unsigned short* __restrict__ z, const float* __restrict__ ss,
    float* __restrict__ out, int E)
{
    const int b = blockIdx.y;
    const int idx = blockIdx.x * 256 + threadIdx.x;  // over 8*E
    const int o = idx / E;
    const int e = idx % E;
    const float sc = ss[((size_t)b * 8 + o) * 2];
    const float sh = ss[((size_t)b * 8 + o) * 2 + 1];
    const float v = bfbits2f(z[((size_t)b * E + e) * 8 + o]) * sc + sh;
    out[(size_t)b * 8 * E + idx] = fmaxf(v, 0.f);
}

extern "C" void kernel_launch(void* const* d_in, const int* in_sizes, int n_in,
                              void* d_out, int out_size, void* d_ws, size_t ws_size,
                              hipStream_t stream)
{
    (void)in_sizes; (void)n_in; (void)out_size; (void)ws_size;

    const float* fe = (const float*)d_in[0];
    const int* gemm0 = (const int*)d_in[4];
    const int* gemm1 = (const int*)d_in[5];
    const int* gemm2 = (const int*)d_in[6];
    const int* gemm3 = (const int*)d_in[7];
    const int* up0 = (const int*)d_in[8];
    const int* up1 = (const int*)d_in[9];
    const int* up2 = (const int*)d_in[10];
    const float* bup0 = (const float*)d_in[12];
    const float* bc0  = (const float*)d_in[14];
    const float* bup1 = (const float*)d_in[16];
    const float* bc1  = (const float*)d_in[18];
    const float* bup2 = (const float*)d_in[20];
    const float* bc2  = (const float*)d_in[22];
    const float* bupf = (const float*)d_in[24];
    const float* bcf  = (const float*)d_in[26];

    unsigned short* wsb = (unsigned short*)d_ws;
    const size_t NP = 8388608;  // 2*32768*128 = max activation elems
    unsigned short* P0 = wsb;
    unsigned short* P1 = wsb + NP;
    unsigned short* P2 = wsb + 2 * NP;
    unsigned short* Bp_up0 = wsb + 3 * NP;       // 5*256*128 = 163840
    unsigned short* Bp_c0  = Bp_up0 + 163840;    // 5*128*128 =  81920
    unsigned short* Bp_up1 = Bp_c0  + 81920;     // 5*128*64  =  40960
    unsigned short* Bp_c1  = Bp_up1 + 40960;     // 5*64*64   =  20480
    unsigned short* Bp_up2 = Bp_c1  + 20480;     // 5*64*32   =  10240
    unsigned short* Bp_c2  = Bp_up2 + 10240;     // 5*32*32   =   5120
    float* fls    = (float*)(Bp_c2 + 5120);
    float* wt_upf = fls;                  // 32*5*8 = 1280
    float* wt_cf  = wt_upf + 1280;        //  8*5*8 =  320
    float* stats0 = wt_cf  + 320;         // 2*128*2 = 512
    float* stats1 = stats0 + 512;         // 2*64*2  = 256
    float* stats2 = stats1 + 256;         // 2*32*2  = 128
    float* stats3 = stats2 + 128;         // 2*8*2   = 32
    float* ss0    = stats3 + 32;
    float* ss1    = ss0 + 512;
    float* ss2    = ss1 + 256;
    float* ss3    = ss2 + 128;

    hipMemsetAsync(stats0, 0, 928 * sizeof(float), stream);

    const dim3 blk(256);

    // input transpose: fe (2,256,16384) fp32 -> P0 (2,16384,256) bf16
    k_transpose_in<<<dim3(16384 / 64, 256 / 64, 2), blk, 0, stream>>>(fe, P0, 256, 16384);

    // weight packing
    k_prep_b<<<dim3(163840 / 256), blk, 0, stream>>>((const float*)d_in[11], Bp_up0, 256, 128);
    k_prep_b<<<dim3(81920 / 256),  blk, 0, stream>>>((const float*)d_in[13], Bp_c0, 128, 128);
    k_prep_b<<<dim3(40960 / 256),  blk, 0, stream>>>((const float*)d_in[15], Bp_up1, 128, 64);
    k_prep_b<<<dim3(20480 / 256),  blk, 0, stream>>>((const float*)d_in[17], Bp_c1, 64, 64);
    k_prep_b<<<dim3(10240 / 256),  blk, 0, stream>>>((const float*)d_in[19], Bp_up2, 64, 32);
    k_prep_b<<<dim3(5120 / 256),   blk, 0, stream>>>((const float*)d_in[21], Bp_c2, 32, 32);
    k_prep_w<<<dim3((1280 + 255) / 256), blk, 0, stream>>>((const float*)d_in[23], wt_upf, 32, 8);
    k_prep_w<<<dim3((320 + 255) / 256),  blk, 0, stream>>>((const float*)d_in[25], wt_cf, 8, 8);

    // ---- stage 0 ----
    k_conv_mfma<256, 128><<<dim3(16384 / 64, 2), blk, 0, stream>>>(P0, gemm0, Bp_up0, bup0, P1, 16384);
    k_unpool_skip<128><<<dim3(32768 * 128 / 256, 2), blk, 0, stream>>>(P1, up0, (const float*)d_in[1], P2, 16384, 32768);
    k_conv_mfma<128, 128><<<dim3(32768 / 64, 2), blk, 0, stream>>>(P2, gemm1, Bp_c0, bc0, P0, 32768);
    k_stats<128><<<dim3(32768 / 256, 2), blk, 0, stream>>>(P0, stats0, 32768);
    k_scale<<<dim3(1), blk, 0, stream>>>(stats0, ss0, 256, 1.f / 32768.f);
    k_norm_relu<128><<<dim3(32768 * 128 / 256, 2), blk, 0, stream>>>(P0, ss0, 32768);

    // ---- stage 1 ----
    k_conv_mfma<128, 64><<<dim3(32768 / 64, 2), blk, 0, stream>>>(P0, gemm1, Bp_up1, bup1, P1, 32768);
    k_unpool_skip<64><<<dim3(65536 * 64 / 256, 2), blk, 0, stream>>>(P1, up1, (const float*)d_in[2], P2, 32768, 65536);
    k_conv_mfma<64, 64><<<dim3(65536 / 64, 2), blk, 0, stream>>>(P2, gemm2, Bp_c1, bc1, P0, 65536);
    k_stats<64><<<dim3(65536 / 256, 2), blk, 0, stream>>>(P0, stats1, 65536);
    k_scale<<<dim3(1), blk, 0, stream>>>(stats1, ss1, 128, 1.f / 65536.f);
    k_norm_relu<64><<<dim3(65536 * 64 / 256, 2), blk, 0, stream>>>(P0, ss1, 65536);

    // ---- stage 2 ----
    k_conv_mfma<64, 32><<<dim3(65536 / 64, 2), blk, 0, stream>>>(P0, gemm2, Bp_up2, bup2, P1, 65536);
    k_unpool_skip<32><<<dim3(131072 * 32 / 256, 2), blk, 0, stream>>>(P1, up2, (const float*)d_in[3], P2, 65536, 131072);
    k_conv_mfma<32, 32><<<dim3(131072 / 64, 2), blk, 0, stream>>>(P2, gemm3, Bp_c2, bc2, P0, 131072);
    k_stats<32><<<dim3(131072 / 256, 2), blk, 0, stream>>>(P0, stats2, 131072);
    k_scale<<<dim3(1), blk, 0, stream>>>(stats2, ss2, 64, 1.f / 131072.f);
    k_norm_relu<32><<<dim3(131072 * 32 / 256, 2), blk, 0, stream>>>(P0, ss2, 131072);

    // ---- final ----
    k_conv_small<32, 8, 4, 2><<<dim3(131072 / 256, 2), blk, 0, stream>>>(P0, gemm3, wt_upf, bupf, P1, 131072);
    k_conv_small<8, 8, 4, 2><<<dim3(131072 / 256, 2), blk, 0, stream>>>(P1, gemm3, wt_cf, bcf, P2, 131072);
    k_stats<8><<<dim3(131072 / 256, 2), blk, 0, stream>>>(P2, stats3, 131072);
    k_scale<<<dim3(1), blk, 0, stream>>>(stats3, ss3, 16, 1.f / 131072.f);
    k_final_out<<<dim3(8 * 131072 / 256, 2), blk, 0, stream>>>(P2, ss3, (float*)d_out, 131072);
}

// Round 4
// 785.707 us; speedup vs baseline: 2.8903x; 1.0199x over previous
//
#include <hip/hip_runtime.h>
#include <hip/hip_bf16.h>
#include <cstdint>
#include <cstddef>

// ---------------------------------------------------------------------------
// MeshDecoder pipeline, round 4.
// bf16 activations, layout (B,E,C) C-contiguous. MFMA convs for C>=32,O>=32;
// VALU conv for O=8. Stats fused into conv epilogues; LDS-tiled unpool+skip.
// ---------------------------------------------------------------------------

typedef short s16x8 __attribute__((ext_vector_type(8)));
typedef unsigned short u16x8 __attribute__((ext_vector_type(8)));
typedef float f32x4 __attribute__((ext_vector_type(4)));

__device__ __forceinline__ float bfbits2f(unsigned short u) {
    unsigned int x = ((unsigned int)u) << 16;
    float f; __builtin_memcpy(&f, &x, sizeof(f)); return f;
}
__device__ __forceinline__ unsigned short f2bfbits(float f) {
    __hip_bfloat16 h = __float2bfloat16(f);
    unsigned short u; __builtin_memcpy(&u, &h, sizeof(u)); return u;
}

// (B,C,E) fp32 -> (B,E,C) bf16 tiled transpose
__global__ __launch_bounds__(256) void k_transpose_in(
    const float* __restrict__ in, unsigned short* __restrict__ out, int C, int E)
{
    __shared__ float tile[64][65];
    const int e0 = blockIdx.x * 64;
    const int c0 = blockIdx.y * 64;
    const int b  = blockIdx.z;
    const float* inb = in + (size_t)b * C * E;
    const int l = threadIdx.x % 64;
    const int g = threadIdx.x / 64;
#pragma unroll
    for (int i = 0; i < 16; ++i) {
        const int c = i * 4 + g;
        tile[c][l] = inb[(size_t)(c0 + c) * E + e0 + l];
    }
    __syncthreads();
    unsigned short* outb = out + (size_t)b * E * C;
#pragma unroll
    for (int i = 0; i < 16; ++i) {
        const int e = i * 4 + g;
        outb[(size_t)(e0 + e) * C + c0 + l] = f2bfbits(tile[l][e]);
    }
}

// W (O,C,5) fp32 -> B-fragment-packed bf16: Bp[((kk*O)+o)*8 + j], k=kk*8+j=s*C+c
__global__ __launch_bounds__(256) void k_prep_b(
    const float* __restrict__ W, unsigned short* __restrict__ Bp, int C, int O)
{
    const int p = blockIdx.x * 256 + threadIdx.x;
    const int total = 5 * C * O;
    if (p >= total) return;
    const int j = p & 7;
    const int t = p >> 3;
    const int o = t % O;
    const int kk = t / O;
    const int k = kk * 8 + j;
    const int s = k / C;
    const int c = k - s * C;
    Bp[p] = f2bfbits(W[((size_t)o * C + c) * 5 + s]);
}

// W (O,C,5) fp32 -> W_T[(c*5+s)*O + o] fp32 (VALU-path weights)
__global__ __launch_bounds__(256) void k_prep_w(
    const float* __restrict__ W, float* __restrict__ Wt, int C, int O)
{
    const int idx = blockIdx.x * 256 + threadIdx.x;
    const int total = C * 5 * O;
    if (idx >= total) return;
    const int k = idx / O;
    const int o = idx % O;
    const int c = k / 5;
    const int s = k - 5 * c;
    Wt[idx] = W[((size_t)o * C + c) * 5 + s];
}

// MFMA mesh_conv, optional fused per-channel stats (sum, sumsq) accumulation.
template<int C, int O, bool STATS>
__global__ __launch_bounds__(256) void k_conv_mfma(
    const unsigned short* __restrict__ x, const int* __restrict__ gm,
    const unsigned short* __restrict__ Bp, const float* __restrict__ bias,
    unsigned short* __restrict__ out, float* __restrict__ stats, int E)
{
    constexpr int NT  = O / 16;
    constexpr int ITS = C / 32;
    static_assert(C % 32 == 0 && O % 16 == 0, "bad cfg");
    const int tid  = threadIdx.x;
    const int wave = tid >> 6;
    const int lane = tid & 63;
    const int m    = lane & 15;
    const int kq   = lane >> 4;
    const int b    = blockIdx.y;
    const int e    = blockIdx.x * 64 + wave * 16 + m;
    const unsigned short* xb = x + (size_t)b * E * C;

    const int4 gi = *reinterpret_cast<const int4*>(gm + 4 * (size_t)e);
    const unsigned short* p0  = xb + (size_t)e * C;
    const unsigned short* pf1 = xb + (size_t)gi.x * C;
    const unsigned short* pf2 = xb + (size_t)gi.y * C;
    const unsigned short* pf3 = xb + (size_t)gi.z * C;
    const unsigned short* pf4 = xb + (size_t)gi.w * C;

    const s16x8* Bp8 = reinterpret_cast<const s16x8*>(Bp);

    f32x4 acc[NT];
#pragma unroll
    for (int nt = 0; nt < NT; ++nt) acc[nt] = (f32x4){0.f, 0.f, 0.f, 0.f};

#pragma unroll
    for (int s = 0; s < 5; ++s) {
        const unsigned short* pa = (s == 0) ? p0 : ((s == 1 || s == 3) ? pf1 : pf2);
        const unsigned short* pb = (s == 0) ? p0 : ((s == 1 || s == 3) ? pf3 : pf4);
        for (int it = 0; it < ITS; ++it) {
            const int c0 = it * 32 + kq * 8;
            s16x8 afrag;
            if (s == 0) {
                afrag = *reinterpret_cast<const s16x8*>(pa + c0);
            } else {
                const s16x8 av = *reinterpret_cast<const s16x8*>(pa + c0);
                const s16x8 bv = *reinterpret_cast<const s16x8*>(pb + c0);
#pragma unroll
                for (int j = 0; j < 8; ++j) {
                    const float fa = bfbits2f((unsigned short)av[j]);
                    const float fb = bfbits2f((unsigned short)bv[j]);
                    const float t = (s < 3) ? (fa + fb) : fabsf(fa - fb);
                    afrag[j] = (short)f2bfbits(t);
                }
            }
            const int kk = s * (C / 8) + it * 4 + kq;
#pragma unroll
            for (int nt = 0; nt < NT; ++nt) {
                const s16x8 bfrag = Bp8[(size_t)kk * O + nt * 16 + m];
                acc[nt] = __builtin_amdgcn_mfma_f32_16x16x32_bf16(afrag, bfrag, acc[nt], 0, 0, 0);
            }
        }
    }

    const int ebase = blockIdx.x * 64 + wave * 16 + kq * 4;
    float ssum[NT], ssq[NT];
#pragma unroll
    for (int nt = 0; nt < NT; ++nt) {
        const int o = nt * 16 + m;
        const float bo = bias[o];
        float s = 0.f, q = 0.f;
#pragma unroll
        for (int r = 0; r < 4; ++r) {
            const float z = acc[nt][r] + bo;
            out[((size_t)b * E + (ebase + r)) * O + o] = f2bfbits(z);
            s += z; q += z * z;
        }
        ssum[nt] = s; ssq[nt] = q;
    }

    if constexpr (STATS) {
        __shared__ float ls[4][2][O];
#pragma unroll
        for (int nt = 0; nt < NT; ++nt) {
            float s = ssum[nt], q = ssq[nt];
            s += __shfl_xor(s, 16); s += __shfl_xor(s, 32);
            q += __shfl_xor(q, 16); q += __shfl_xor(q, 32);
            if (kq == 0) { ls[wave][0][nt * 16 + m] = s; ls[wave][1][nt * 16 + m] = q; }
        }
        __syncthreads();
        if (tid < O) {
            const float S = ls[0][0][tid] + ls[1][0][tid] + ls[2][0][tid] + ls[3][0][tid];
            const float Q = ls[0][1][tid] + ls[1][1][tid] + ls[2][1][tid] + ls[3][1][tid];
            atomicAdd(&stats[((size_t)b * O + tid) * 2], S);
            atomicAdd(&stats[((size_t)b * O + tid) * 2 + 1], Q);
        }
    }
}

// VALU mesh_conv for O=8: one e per thread (no duplicate gathers), 16B row loads.
template<int C, int O, bool STATS>
__global__ __launch_bounds__(256) void k_conv_small(
    const unsigned short* __restrict__ x, const int* __restrict__ gm,
    const float* __restrict__ Wt, const float* __restrict__ bias,
    unsigned short* __restrict__ out, float* __restrict__ stats, int E)
{
    static_assert(O == 8 && C % 8 == 0, "bad cfg");
    __shared__ float ls[2 * O];
    const int tid = threadIdx.x;
    if constexpr (STATS) {
        if (tid < 2 * O) ls[tid] = 0.f;
        __syncthreads();
    }
    const int b = blockIdx.y;
    const int e = blockIdx.x * 256 + tid;
    const unsigned short* xb = x + (size_t)b * E * C;
    const int4 gi = *reinterpret_cast<const int4*>(gm + 4 * (size_t)e);
    const unsigned short* rp[5] = {
        xb + (size_t)e * C, xb + (size_t)gi.x * C, xb + (size_t)gi.y * C,
        xb + (size_t)gi.z * C, xb + (size_t)gi.w * C };

    float acc[O];
#pragma unroll
    for (int o = 0; o < O; ++o) acc[o] = bias[o];

#pragma unroll
    for (int c = 0; c < C; c += 8) {
        u16x8 rv[5];
#pragma unroll
        for (int k = 0; k < 5; ++k) rv[k] = *reinterpret_cast<const u16x8*>(rp[k] + c);
#pragma unroll
        for (int cc = 0; cc < 8; ++cc) {
            const float x0 = bfbits2f(rv[0][cc]);
            const float f1 = bfbits2f(rv[1][cc]);
            const float f2 = bfbits2f(rv[2][cc]);
            const float f3 = bfbits2f(rv[3][cc]);
            const float f4 = bfbits2f(rv[4][cc]);
            const float gv[5] = { x0, f1 + f3, f2 + f4, fabsf(f1 - f3), fabsf(f2 - f4) };
            const float* wbase = Wt + (size_t)(c + cc) * 5 * O;
#pragma unroll
            for (int s = 0; s < 5; ++s)
#pragma unroll
                for (int o = 0; o < O; ++o)
                    acc[o] += gv[s] * wbase[s * O + o];
        }
    }

    u16x8 ov;
#pragma unroll
    for (int o = 0; o < O; ++o) ov[o] = f2bfbits(acc[o]);
    *reinterpret_cast<u16x8*>(out + ((size_t)b * E + e) * O) = ov;

    if constexpr (STATS) {
#pragma unroll
        for (int o = 0; o < O; ++o) {
            atomicAdd(&ls[o * 2], acc[o]);
            atomicAdd(&ls[o * 2 + 1], acc[o] * acc[o]);
        }
        __syncthreads();
        if (tid < 2 * O) atomicAdd(&stats[(size_t)b * 2 * O + tid], ls[tid]);
    }
}

// x1[b,e,o] = y[b, up[e], o] + skip[b, o, e]  -- LDS-tiled (coalesced skip reads)
template<int O>
__global__ __launch_bounds__(256) void k_unpool_skip(
    const unsigned short* __restrict__ y, const int* __restrict__ up,
    const float* __restrict__ skip, unsigned short* __restrict__ out,
    int Ein, int Eout)
{
    __shared__ float sk[O][65];
    const int b  = blockIdx.y;
    const int e0 = blockIdx.x * 64;
    const int t  = threadIdx.x;
    constexpr int L = O / 16;   // float4 loads per thread
#pragma unroll
    for (int i = 0; i < L; ++i) {
        const int flat = i * 256 + t;
        const int o = flat >> 4;
        const int el4 = (flat & 15) * 4;
        const float4 v = *reinterpret_cast<const float4*>(
            skip + ((size_t)b * O + o) * Eout + e0 + el4);
        sk[o][el4]     = v.x;
        sk[o][el4 + 1] = v.y;
        sk[o][el4 + 2] = v.z;
        sk[o][el4 + 3] = v.w;
    }
    __syncthreads();
    constexpr int OG  = O / 4;       // threads per e
    constexpr int EPP = 256 / OG;    // e's per pass
    const int o4  = (t % OG) * 4;
    const int elg = t / OG;
#pragma unroll
    for (int p = 0; p < 64 / EPP; ++p) {
        const int el = p * EPP + elg;
        const int e  = e0 + el;
        const int u  = up[e];
        const ushort4 yv = *reinterpret_cast<const ushort4*>(
            y + ((size_t)b * Ein + u) * O + o4);
        ushort4 ov;
        ov.x = f2bfbits(bfbits2f(yv.x) + sk[o4 + 0][el]);
        ov.y = f2bfbits(bfbits2f(yv.y) + sk[o4 + 1][el]);
        ov.z = f2bfbits(bfbits2f(yv.z) + sk[o4 + 2][el]);
        ov.w = f2bfbits(bfbits2f(yv.w) + sk[o4 + 3][el]);
        *reinterpret_cast<ushort4*>(out + ((size_t)b * Eout + e) * O + o4) = ov;
    }
}

// stats -> scale/shift
__global__ __launch_bounds__(256) void k_scale(
    const float* __restrict__ stats, float* __restrict__ ss, int BC, float invE)
{
    const int t = threadIdx.x;
    if (t < BC) {
        const float sum = stats[t * 2];
        const float sq  = stats[t * 2 + 1];
        const float m   = sum * invE;
        const float var = fmaxf(sq * invE - m * m, 0.f);
        const float sc  = rsqrtf(var + 1e-5f);
        ss[t * 2] = sc;
        ss[t * 2 + 1] = -m * sc;
    }
}

// in-place relu((x)*sc + sh), vectorized ushort8
template<int C>
__global__ __launch_bounds__(256) void k_norm_relu(
    unsigned short* __restrict__ x, const float* __restrict__ ss, int E)
{
    const int b = blockIdx.y;
    const size_t i8 = ((size_t)blockIdx.x * 256 + threadIdx.x) * 8;
    const int c0 = (int)(i8 % C);
    unsigned short* p = x + (size_t)b * E * C + i8;
    const u16x8 v = *reinterpret_cast<const u16x8*>(p);
    u16x8 r;
#pragma unroll
    for (int j = 0; j < 8; ++j) {
        const float sc = ss[(b * C + c0 + j) * 2];
        const float sh = ss[(b * C + c0 + j) * 2 + 1];
        r[j] = f2bfbits(fmaxf(bfbits2f(v[j]) * sc + sh, 0.f));
    }
    *reinterpret_cast<u16x8*>(p) = r;
}

// final: (B,E,8) bf16 -> norm+relu -> (B,8,E) fp32
__global__ __launch_bounds__(256) void k_final_out(
    const unsigned short* __restrict__ z, const float* __restrict__ ss,
    float* __restrict__ out, int E)
{
    const int b = blockIdx.y;
    const int idx = blockIdx.x * 256 + threadIdx.x;  // over 8*E
    const int o = idx / E;
    const int e = idx % E;
    const float sc = ss[((size_t)b * 8 + o) * 2];
    const float sh = ss[((size_t)b * 8 + o) * 2 + 1];
    const float v = bfbits2f(z[((size_t)b * E + e) * 8 + o]) * sc + sh;
    out[(size_t)b * 8 * E + idx] = fmaxf(v, 0.f);
}

extern "C" void kernel_launch(void* const* d_in, const int* in_sizes, int n_in,
                              void* d_out, int out_size, void* d_ws, size_t ws_size,
                              hipStream_t stream)
{
    (void)in_sizes; (void)n_in; (void)out_size; (void)ws_size;

    const float* fe = (const float*)d_in[0];
    const int* gemm0 = (const int*)d_in[4];
    const int* gemm1 = (const int*)d_in[5];
    const int* gemm2 = (const int*)d_in[6];
    const int* gemm3 = (const int*)d_in[7];
    const int* up0 = (const int*)d_in[8];
    const int* up1 = (const int*)d_in[9];
    const int* up2 = (const int*)d_in[10];
    const float* bup0 = (const float*)d_in[12];
    const float* bc0  = (const float*)d_in[14];
    const float* bup1 = (const float*)d_in[16];
    const float* bc1  = (const float*)d_in[18];
    const float* bup2 = (const float*)d_in[20];
    const float* bc2  = (const float*)d_in[22];
    const float* bupf = (const float*)d_in[24];
    const float* bcf  = (const float*)d_in[26];

    unsigned short* wsb = (unsigned short*)d_ws;
    const size_t NP = 8388608;  // 2*32768*128 = max activation elems
    unsigned short* P0 = wsb;
    unsigned short* P1 = wsb + NP;
    unsigned short* P2 = wsb + 2 * NP;
    unsigned short* Bp_up0 = wsb + 3 * NP;       // 5*256*128 = 163840
    unsigned short* Bp_c0  = Bp_up0 + 163840;    // 5*128*128 =  81920
    unsigned short* Bp_up1 = Bp_c0  + 81920;     // 5*128*64  =  40960
    unsigned short* Bp_c1  = Bp_up1 + 40960;     // 5*64*64   =  20480
    unsigned short* Bp_up2 = Bp_c1  + 20480;     // 5*64*32   =  10240
    unsigned short* Bp_c2  = Bp_up2 + 10240;     // 5*32*32   =   5120
    float* fls    = (float*)(Bp_c2 + 5120);
    float* wt_upf = fls;                  // 32*5*8 = 1280
    float* wt_cf  = wt_upf + 1280;        //  8*5*8 =  320
    float* stats0 = wt_cf  + 320;         // 2*128*2 = 512
    float* stats1 = stats0 + 512;         // 2*64*2  = 256
    float* stats2 = stats1 + 256;         // 2*32*2  = 128
    float* stats3 = stats2 + 128;         // 2*8*2   = 32
    float* ss0    = stats3 + 32;
    float* ss1    = ss0 + 512;
    float* ss2    = ss1 + 256;
    float* ss3    = ss2 + 128;

    hipMemsetAsync(stats0, 0, 928 * sizeof(float), stream);

    const dim3 blk(256);

    // input transpose: fe (2,256,16384) fp32 -> P0 (2,16384,256) bf16
    k_transpose_in<<<dim3(16384 / 64, 256 / 64, 2), blk, 0, stream>>>(fe, P0, 256, 16384);

    // weight packing
    k_prep_b<<<dim3(163840 / 256), blk, 0, stream>>>((const float*)d_in[11], Bp_up0, 256, 128);
    k_prep_b<<<dim3(81920 / 256),  blk, 0, stream>>>((const float*)d_in[13], Bp_c0, 128, 128);
    k_prep_b<<<dim3(40960 / 256),  blk, 0, stream>>>((const float*)d_in[15], Bp_up1, 128, 64);
    k_prep_b<<<dim3(20480 / 256),  blk, 0, stream>>>((const float*)d_in[17], Bp_c1, 64, 64);
    k_prep_b<<<dim3(10240 / 256),  blk, 0, stream>>>((const float*)d_in[19], Bp_up2, 64, 32);
    k_prep_b<<<dim3(5120 / 256),   blk, 0, stream>>>((const float*)d_in[21], Bp_c2, 32, 32);
    k_prep_w<<<dim3((1280 + 255) / 256), blk, 0, stream>>>((const float*)d_in[23], wt_upf, 32, 8);
    k_prep_w<<<dim3((320 + 255) / 256),  blk, 0, stream>>>((const float*)d_in[25], wt_cf, 8, 8);

    // ---- stage 0 ----
    k_conv_mfma<256, 128, false><<<dim3(16384 / 64, 2), blk, 0, stream>>>(P0, gemm0, Bp_up0, bup0, P1, nullptr, 16384);
    k_unpool_skip<128><<<dim3(32768 / 64, 2), blk, 0, stream>>>(P1, up0, (const float*)d_in[1], P2, 16384, 32768);
    k_conv_mfma<128, 128, true><<<dim3(32768 / 64, 2), blk, 0, stream>>>(P2, gemm1, Bp_c0, bc0, P0, stats0, 32768);
    k_scale<<<dim3(1), blk, 0, stream>>>(stats0, ss0, 256, 1.f / 32768.f);
    k_norm_relu<128><<<dim3(32768 * 128 / 2048, 2), blk, 0, stream>>>(P0, ss0, 32768);

    // ---- stage 1 ----
    k_conv_mfma<128, 64, false><<<dim3(32768 / 64, 2), blk, 0, stream>>>(P0, gemm1, Bp_up1, bup1, P1, nullptr, 32768);
    k_unpool_skip<64><<<dim3(65536 / 64, 2), blk, 0, stream>>>(P1, up1, (const float*)d_in[2], P2, 32768, 65536);
    k_conv_mfma<64, 64, true><<<dim3(65536 / 64, 2), blk, 0, stream>>>(P2, gemm2, Bp_c1, bc1, P0, stats1, 65536);
    k_scale<<<dim3(1), blk, 0, stream>>>(stats1, ss1, 128, 1.f / 65536.f);
    k_norm_relu<64><<<dim3(65536 * 64 / 2048, 2), blk, 0, stream>>>(P0, ss1, 65536);

    // ---- stage 2 ----
    k_conv_mfma<64, 32, false><<<dim3(65536 / 64, 2), blk, 0, stream>>>(P0, gemm2, Bp_up2, bup2, P1, nullptr, 65536);
    k_unpool_skip<32><<<dim3(131072 / 64, 2), blk, 0, stream>>>(P1, up2, (const float*)d_in[3], P2, 65536, 131072);
    k_conv_mfma<32, 32, true><<<dim3(131072 / 64, 2), blk, 0, stream>>>(P2, gemm3, Bp_c2, bc2, P0, stats2, 131072);
    k_scale<<<dim3(1), blk, 0, stream>>>(stats2, ss2, 64, 1.f / 131072.f);
    k_norm_relu<32><<<dim3(131072 * 32 / 2048, 2), blk, 0, stream>>>(P0, ss2, 131072);

    // ---- final ----
    k_conv_small<32, 8, false><<<dim3(131072 / 256, 2), blk, 0, stream>>>(P0, gemm3, wt_upf, bupf, P1, nullptr, 131072);
    k_conv_small<8, 8, true><<<dim3(131072 / 256, 2), blk, 0, stream>>>(P1, gemm3, wt_cf, bcf, P2, stats3, 131072);
    k_scale<<<dim3(1), blk, 0, stream>>>(stats3, ss3, 16, 1.f / 131072.f);
    k_final_out<<<dim3(8 * 131072 / 256, 2), blk, 0, stream>>>(P2, ss3, (float*)d_out, 131072);
}